// Round 7
// baseline (35.833 us; speedup 1.0000x reference)
//
#include <hip/hip_runtime.h>

#define BB 32
#define HH 512
#define WW 512

constexpr int PLANE = HH * WW;                       // 262144
constexpr int BLOCK = 256;
constexpr int GRID = 1024;                           // 4 blocks/CU x 256 CUs
constexpr int NPAIRS = BB * HH / 2;                  // 8192 row-pairs
constexpr int WAVES_TOTAL = GRID * 4;                // 4096 waves
constexpr int ITERS = NPAIRS / WAVES_TOTAL;          // 2 row-pairs per wave
constexpr float INV_NPIX = 1.0f / 8388608.0f;        // 2^-23, exact

__global__ __launch_bounds__(256, 4) void edge_loss_kernel(
    const float* __restrict__ pred,
    const int* __restrict__ tgt,
    float* __restrict__ out)
{
    const int lane = threadIdx.x & 63;
    const int wid  = threadIdx.x >> 6;
    const int wA = 4 * lane;          // chunk A: px wA..wA+3
    const int wB = 256 + 4 * lane;    // chunk B: px wB..wB+3

    const float L2E = 1.4426950408889634f;
    const float LN2 = 0.6931471805599453f;
    float sum = 0.0f;

    #pragma unroll 1
    for (int it = 0; it < ITERS; ++it) {
        const int gw = blockIdx.x * 4 + wid + it * WAVES_TOTAL;  // row-pair id
        const int r0 = gw * 2;                 // even global row (b*512 + h0)
        const int h0 = r0 & (HH - 1);          // even, 0..510
        const int b  = r0 >> 9;
        const int base0 = r0 * WW;

        // target rows: r0-1 (maybe), r0, r0+1, r0+2 (maybe) — 16 B lane stride
        const int4 t0A4 = *reinterpret_cast<const int4*>(tgt + base0 + wA);
        const int4 t0B4 = *reinterpret_cast<const int4*>(tgt + base0 + wB);
        const int4 t1A4 = *reinterpret_cast<const int4*>(tgt + base0 + WW + wA);
        const int4 t1B4 = *reinterpret_cast<const int4*>(tgt + base0 + WW + wB);
        const int t0A[4] = { t0A4.x, t0A4.y, t0A4.z, t0A4.w };
        const int t0B[4] = { t0B4.x, t0B4.y, t0B4.z, t0B4.w };
        const int t1A[4] = { t1A4.x, t1A4.y, t1A4.z, t1A4.w };
        const int t1B[4] = { t1B4.x, t1B4.y, t1B4.z, t1B4.w };

        const bool hasu = (h0 > 0);        // row0's up exists
        const bool hasd = (h0 < HH - 2);   // row1's down exists
        int tmA[4], tmB[4], t2A[4], t2B[4];
        if (hasu) {
            const int4 a  = *reinterpret_cast<const int4*>(tgt + base0 - WW + wA);
            const int4 bb = *reinterpret_cast<const int4*>(tgt + base0 - WW + wB);
            tmA[0]=a.x; tmA[1]=a.y; tmA[2]=a.z; tmA[3]=a.w;
            tmB[0]=bb.x; tmB[1]=bb.y; tmB[2]=bb.z; tmB[3]=bb.w;
        }
        if (hasd) {
            const int4 a  = *reinterpret_cast<const int4*>(tgt + base0 + 2 * WW + wA);
            const int4 bb = *reinterpret_cast<const int4*>(tgt + base0 + 2 * WW + wB);
            t2A[0]=a.x; t2A[1]=a.y; t2A[2]=a.z; t2A[3]=a.w;
            t2B[0]=bb.x; t2B[1]=bb.y; t2B[2]=bb.z; t2B[3]=bb.w;
        }

        // predictions: 2 rows x 3 planes x 2 chunks
        const float* pp0 = pred + (size_t)(b * 3) * PLANE + (size_t)h0 * WW;
        const float4 p0A0 = *reinterpret_cast<const float4*>(pp0 + wA);
        const float4 p0B0 = *reinterpret_cast<const float4*>(pp0 + wB);
        const float4 p0A1 = *reinterpret_cast<const float4*>(pp0 + PLANE + wA);
        const float4 p0B1 = *reinterpret_cast<const float4*>(pp0 + PLANE + wB);
        const float4 p0A2 = *reinterpret_cast<const float4*>(pp0 + 2 * PLANE + wA);
        const float4 p0B2 = *reinterpret_cast<const float4*>(pp0 + 2 * PLANE + wB);
        const float4 p1A0 = *reinterpret_cast<const float4*>(pp0 + WW + wA);
        const float4 p1B0 = *reinterpret_cast<const float4*>(pp0 + WW + wB);
        const float4 p1A1 = *reinterpret_cast<const float4*>(pp0 + WW + PLANE + wA);
        const float4 p1B1 = *reinterpret_cast<const float4*>(pp0 + WW + PLANE + wB);
        const float4 p1A2 = *reinterpret_cast<const float4*>(pp0 + WW + 2 * PLANE + wA);
        const float4 p1B2 = *reinterpret_cast<const float4*>(pp0 + WW + 2 * PLANE + wB);

        auto proc4 = [&](const int c[4], const int* u, const int* d,
                         bool has_up, bool has_down,
                         int ld_, int le_, int rd_, int re_,
                         const float4& P0, const float4& P1, const float4& P2) {
            const float C0[4] = { P0.x, P0.y, P0.z, P0.w };
            const float C1[4] = { P1.x, P1.y, P1.z, P1.w };
            const float C2[4] = { P2.x, P2.y, P2.z, P2.w };
            #pragma unroll
            for (int i = 0; i < 4; ++i) {
                const int lv_d = (i == 0) ? ld_ : c[i - 1];
                const int lv_e = (i == 0) ? le_ : c[i - 1];
                const int rv_d = (i == 3) ? rd_ : c[i + 1];
                const int rv_e = (i == 3) ? re_ : c[i + 1];
                int dil = max(c[i], max(lv_d, rv_d));
                int ero = min(c[i], min(lv_e, rv_e));
                if (has_up)   { dil = max(dil, u[i]); ero = min(ero, u[i]); }
                if (has_down) { dil = max(dil, d[i]); ero = min(ero, d[i]); }
                const int edge = dil ^ ero;

                const float pa = C0[i], pb = C1[i], pc = C2[i];
                const float s = __builtin_amdgcn_exp2f(pa * L2E)
                              + __builtin_amdgcn_exp2f(pb * L2E)
                              + __builtin_amdgcn_exp2f(pc * L2E);
                const float lse = LN2 * __builtin_amdgcn_logf(s);
                const float pt  = (c[i] == 0) ? pa : ((c[i] == 1) ? pb : pc);
                const float wgt = fmaf(2.0f, (float)edge, 1.0f);
                sum = fmaf(lse - pt, wgt, sum);
            }
        };

        auto procrow = [&](const int cA[4], const int cB[4],
                           const int* uA, const int* uB, const int* dA, const int* dB,
                           bool has_up, bool has_down,
                           const float4& PA0, const float4& PA1, const float4& PA2,
                           const float4& PB0, const float4& PB1, const float4& PB2) {
            const int lA = __shfl_up(cA[3], 1, 64);
            const int lB = __shfl_up(cB[3], 1, 64);
            const int rA = __shfl_down(cA[0], 1, 64);
            const int rB = __shfl_down(cB[0], 1, 64);
            const int a3_63 = __shfl(cA[3], 63, 64);   // px 255
            const int b0_0  = __shfl(cB[0], 0, 64);    // px 256
            const int leftA_d  = (lane == 0)  ? 0     : lA;
            const int leftA_e  = (lane == 0)  ? 255   : lA;
            const int leftB_v  = (lane == 0)  ? a3_63 : lB;
            const int rightA_v = (lane == 63) ? b0_0  : rA;
            const int rightB_d = (lane == 63) ? 0     : rB;
            const int rightB_e = (lane == 63) ? 255   : rB;
            proc4(cA, uA, dA, has_up, has_down, leftA_d, leftA_e, rightA_v, rightA_v, PA0, PA1, PA2);
            proc4(cB, uB, dB, has_up, has_down, leftB_v, leftB_v, rightB_d, rightB_e, PB0, PB1, PB2);
        };

        // row 0: up = r0-1 (guarded), down = row 1 (always)
        procrow(t0A, t0B, tmA, tmB, t1A, t1B, hasu, true,
                p0A0, p0A1, p0A2, p0B0, p0B1, p0B2);
        // row 1: up = row 0 (always), down = r0+2 (guarded)
        procrow(t1A, t1B, t0A, t0B, t2A, t2B, true, hasd,
                p1A0, p1A1, p1A2, p1B0, p1B1, p1B2);
    }

    // wave reduce then block reduce -> one fire-and-forget atomic per block
    #pragma unroll
    for (int off = 32; off; off >>= 1)
        sum += __shfl_down(sum, off, 64);

    __shared__ float wsum[4];
    if (lane == 0) wsum[wid] = sum;
    __syncthreads();
    if (threadIdx.x == 0) {
        const float blockSum = wsum[0] + wsum[1] + wsum[2] + wsum[3];
        atomicAdd(out, blockSum * INV_NPIX);   // non-returning: pipelines at L2
    }
}

extern "C" void kernel_launch(void* const* d_in, const int* in_sizes, int n_in,
                              void* d_out, int out_size, void* d_ws, size_t ws_size,
                              hipStream_t stream) {
    const float* pred = (const float*)d_in[0];
    const int*   tgt  = (const int*)d_in[1];
    float* out = (float*)d_out;

    hipMemsetAsync(out, 0, sizeof(float), stream);   // atomics accumulate into out
    edge_loss_kernel<<<GRID, BLOCK, 0, stream>>>(pred, tgt, out);
}

// Round 8
// 27.583 us; speedup vs baseline: 1.2991x; 1.2991x over previous
//
#include <hip/hip_runtime.h>

#define BB 32
#define HH 512
#define WW 512

constexpr int PLANE = HH * WW;                       // 262144
constexpr long long NPIX = (long long)BB * HH * WW;  // 8,388,608
constexpr int BLOCK = 256;
constexpr int GRID = 1024;                           // 4096 waves; 1 wave = 4 rows
constexpr int NWAVES = GRID * 4;                     // 4096

__global__ __launch_bounds__(256) void edge_loss_kernel(
    const float* __restrict__ pred,
    const int* __restrict__ tgt,
    float* __restrict__ partial)
{
    const int lane = threadIdx.x & 63;
    const int wid  = threadIdx.x >> 6;
    const int gw   = blockIdx.x * 4 + wid;   // 0..4095
    const int r0   = gw * 4;                 // first of 4 consecutive rows
    const int h0   = r0 & (HH - 1);          // 0..508, step 4 (never crosses batch)
    const int b    = r0 >> 9;
    const int wA   = 4 * lane;               // chunk A: px wA..wA+3
    const int wB   = 256 + 4 * lane;         // chunk B: px wB..wB+3
    const int base = r0 * WW;

    const bool hasu = (h0 > 0);              // row r0-1 exists
    const bool hasd = (h0 < HH - 4);         // row r0+4 exists

    // target rows r0-1 .. r0+4  ->  index 0..5 (0 and 5 guarded)
    int tA[6][4], tB[6][4];
    #pragma unroll
    for (int k = 0; k < 4; ++k) {
        const int4 a  = *reinterpret_cast<const int4*>(tgt + base + k * WW + wA);
        const int4 bb = *reinterpret_cast<const int4*>(tgt + base + k * WW + wB);
        tA[k+1][0]=a.x;  tA[k+1][1]=a.y;  tA[k+1][2]=a.z;  tA[k+1][3]=a.w;
        tB[k+1][0]=bb.x; tB[k+1][1]=bb.y; tB[k+1][2]=bb.z; tB[k+1][3]=bb.w;
    }
    if (hasu) {
        const int4 a  = *reinterpret_cast<const int4*>(tgt + base - WW + wA);
        const int4 bb = *reinterpret_cast<const int4*>(tgt + base - WW + wB);
        tA[0][0]=a.x;  tA[0][1]=a.y;  tA[0][2]=a.z;  tA[0][3]=a.w;
        tB[0][0]=bb.x; tB[0][1]=bb.y; tB[0][2]=bb.z; tB[0][3]=bb.w;
    }
    if (hasd) {
        const int4 a  = *reinterpret_cast<const int4*>(tgt + base + 4 * WW + wA);
        const int4 bb = *reinterpret_cast<const int4*>(tgt + base + 4 * WW + wB);
        tA[5][0]=a.x;  tA[5][1]=a.y;  tA[5][2]=a.z;  tA[5][3]=a.w;
        tB[5][0]=bb.x; tB[5][1]=bb.y; tB[5][2]=bb.z; tB[5][3]=bb.w;
    }

    const float L2E = 1.4426950408889634f;
    const float LN2 = 0.6931471805599453f;
    float sum = 0.0f;

    auto proc4 = [&](const int c[4], const int u[4], const int d[4],
                     bool has_up, bool has_down,
                     int ld_, int le_, int rd_, int re_,
                     const float4& P0, const float4& P1, const float4& P2) {
        const float C0[4] = { P0.x, P0.y, P0.z, P0.w };
        const float C1[4] = { P1.x, P1.y, P1.z, P1.w };
        const float C2[4] = { P2.x, P2.y, P2.z, P2.w };
        #pragma unroll
        for (int i = 0; i < 4; ++i) {
            const int lv_d = (i == 0) ? ld_ : c[i - 1];
            const int lv_e = (i == 0) ? le_ : c[i - 1];
            const int rv_d = (i == 3) ? rd_ : c[i + 1];
            const int rv_e = (i == 3) ? re_ : c[i + 1];
            int dil = max(c[i], max(lv_d, rv_d));
            int ero = min(c[i], min(lv_e, rv_e));
            if (has_up)   { dil = max(dil, u[i]); ero = min(ero, u[i]); }  // wave-uniform
            if (has_down) { dil = max(dil, d[i]); ero = min(ero, d[i]); }
            const int edge = dil ^ ero;

            const float pa = C0[i], pb = C1[i], pc = C2[i];
            const float s = __builtin_amdgcn_exp2f(pa * L2E)
                          + __builtin_amdgcn_exp2f(pb * L2E)
                          + __builtin_amdgcn_exp2f(pc * L2E);
            const float lse = LN2 * __builtin_amdgcn_logf(s);
            const float pt  = (c[i] == 0) ? pa : ((c[i] == 1) ? pb : pc);
            const float wgt = fmaf(2.0f, (float)edge, 1.0f);
            sum = fmaf(lse - pt, wgt, sum);
        }
    };

    #pragma unroll
    for (int k = 0; k < 4; ++k) {
        const int* cA = tA[k + 1];
        const int* cB = tB[k + 1];
        const bool has_up   = (k == 0) ? hasu : true;
        const bool has_down = (k == 3) ? hasd : true;

        // predictions for row r0+k: 3 planes x 2 chunks
        const float* pp = pred + (size_t)(b * 3) * PLANE + (size_t)(h0 + k) * WW;
        const float4 PA0 = *reinterpret_cast<const float4*>(pp + wA);
        const float4 PB0 = *reinterpret_cast<const float4*>(pp + wB);
        const float4 PA1 = *reinterpret_cast<const float4*>(pp + PLANE + wA);
        const float4 PB1 = *reinterpret_cast<const float4*>(pp + PLANE + wB);
        const float4 PA2 = *reinterpret_cast<const float4*>(pp + 2 * PLANE + wA);
        const float4 PB2 = *reinterpret_cast<const float4*>(pp + 2 * PLANE + wB);

        // cross-lane left/right chunk-boundary neighbors for this row
        const int lA = __shfl_up(cA[3], 1, 64);
        const int lB = __shfl_up(cB[3], 1, 64);
        const int rA = __shfl_down(cA[0], 1, 64);
        const int rB = __shfl_down(cB[0], 1, 64);
        const int a3_63 = __shfl(cA[3], 63, 64);   // px 255
        const int b0_0  = __shfl(cB[0], 0, 64);    // px 256
        const int leftA_d  = (lane == 0)  ? 0     : lA;
        const int leftA_e  = (lane == 0)  ? 255   : lA;
        const int leftB_v  = (lane == 0)  ? a3_63 : lB;
        const int rightA_v = (lane == 63) ? b0_0  : rA;
        const int rightB_d = (lane == 63) ? 0     : rB;
        const int rightB_e = (lane == 63) ? 255   : rB;

        proc4(cA, tA[k], tA[k + 2], has_up, has_down,
              leftA_d, leftA_e, rightA_v, rightA_v, PA0, PA1, PA2);
        proc4(cB, tB[k], tB[k + 2], has_up, has_down,
              leftB_v, leftB_v, rightB_d, rightB_e, PB0, PB1, PB2);
    }

    // wave reduce -> one float per wave, no LDS, no barrier
    #pragma unroll
    for (int off = 32; off; off >>= 1)
        sum += __shfl_down(sum, off, 64);
    if (lane == 0) partial[gw] = sum;
}

__global__ __launch_bounds__(256) void finalize_kernel(
    const float* __restrict__ partial, float* __restrict__ out)
{
    double s = 0.0;
    #pragma unroll
    for (int i = 0; i < NWAVES / (256 * 4); ++i) {   // 4 iterations of float4
        const float4 v = *reinterpret_cast<const float4*>(partial + i * 1024 + threadIdx.x * 4);
        s += (double)v.x + (double)v.y + (double)v.z + (double)v.w;
    }
    #pragma unroll
    for (int off = 32; off; off >>= 1)
        s += __shfl_down(s, off, 64);
    __shared__ double wsum[4];
    const int lane = threadIdx.x & 63;
    if (lane == 0) wsum[threadIdx.x >> 6] = s;
    __syncthreads();
    if (threadIdx.x == 0)
        out[0] = (float)((wsum[0] + wsum[1] + wsum[2] + wsum[3]) / (double)NPIX);
}

extern "C" void kernel_launch(void* const* d_in, const int* in_sizes, int n_in,
                              void* d_out, int out_size, void* d_ws, size_t ws_size,
                              hipStream_t stream) {
    const float* pred = (const float*)d_in[0];
    const int*   tgt  = (const int*)d_in[1];
    float* partial = (float*)d_ws;            // 4096 * 4 B = 16 KiB
    float* out     = (float*)d_out;

    edge_loss_kernel<<<GRID, BLOCK, 0, stream>>>(pred, tgt, partial);
    finalize_kernel<<<1, BLOCK, 0, stream>>>(partial, out);
}